// Round 5
// baseline (885.857 us; speedup 1.0000x reference)
//
#include <hip/hip_runtime.h>
#include <hip/hip_cooperative_groups.h>

namespace cg = cooperative_groups;

#define NF 16
#define HIDN 32
#define NB 32
#define NN 64
#define EPSV 1e-8f

typedef _Float16 f16x8 __attribute__((ext_vector_type(8)));
typedef float f32x4 __attribute__((ext_vector_type(4)));

// Workspace layout (float offsets), all regions overwritten before read each call:
//   slotbits : 0    (16)   per-layer sigma bits (block0 of pre-phase writes, edge reads)
//   redzone  : 16   (256)  per-block absmax partials (update writes, pre reduces)
//   s        : 576  (32768)
//   vec      : 33344 (98304)
//   aggs     : 131648 (8*32768)
//   aggv     : 393792 (8*98304)
//   B2       : 1180224 (2048*128 fp32, sigma-scaled)
//   A2       : 1442368 (2048*4096 fp16, sigma-scaled)
#define SLOT_OFF 0
#define RED_OFF  16
#define S_OFF    576
#define VEC_OFF  33344
#define AGGS_OFF 131648
#define AGGV_OFF 393792
#define B2_OFF   1180224
#define A2_OFF   1442368

__device__ __forceinline__ void sigma_from_bits(unsigned mb, float* sig, float* invs) {
    int ex = (int)((mb >> 23) & 0xFF);
    if (ex == 0) { *sig = 1.f; *invs = 1.f; return; }
    *sig  = __uint_as_float((unsigned)(253 - ex) << 23);  // 2^(126-ex)
    *invs = __uint_as_float((unsigned)(ex + 1) << 23);    // 2^(ex-126)
}

__global__ __launch_bounds__(512, 2) void k_all(
        const float* __restrict__ pos, const float* __restrict__ v,
        const float* __restrict__ z,
        const float* __restrict__ w_s_in, const float* __restrict__ w_v_in,
        const float* __restrict__ rw1, const float* __restrict__ rb1,
        const float* __restrict__ rw2, const float* __restrict__ rb2,
        const float* __restrict__ sws, const float* __restrict__ swv,
        const float* __restrict__ wvo,
        float* __restrict__ out, float* __restrict__ wsf) {
    cg::grid_group grid = cg::this_grid();
    __shared__ float smem[1024];

    unsigned* slotbits = (unsigned*)(wsf + SLOT_OFF);
    float* redzone = wsf + RED_OFF;
    float* s    = wsf + S_OFF;
    float* vec  = wsf + VEC_OFF;
    float* aggs = wsf + AGGS_OFF;
    float* aggv = wsf + AGGV_OFF;
    float* B2   = wsf + B2_OFF;
    _Float16* A2 = (_Float16*)(wsf + A2_OFF);

    const int blk = blockIdx.x;
    const int tid = threadIdx.x;

    for (int l = 0; l < 3; ++l) {
        // ================= PRE: build A2,B2 (+ sigma) =================
        {
            float* s_sh   = smem;         // [8][16]
            float* vec_sh = smem + 128;   // [8][48]
            float* red    = smem + 512;   // [512]
            int node0 = blk * 8;
            int k = tid >> 6, tt = tid & 63;
            int node = node0 + k;
            float sigma;
            if (l == 0) {
                sigma = 1.f;
                if (tt < 16) {
                    float val = z[node] * w_s_in[tt];
                    s_sh[k * 16 + tt] = val;
                    s[node * 16 + tt] = val;
                } else {
                    int q = tt - 16, c = q / 3, d = q % 3;
                    float val = v[node * 3 + d] * w_v_in[c];
                    vec_sh[k * 48 + q] = val;
                    vec[node * 48 + q] = val;
                }
                if (blk == 0 && tid == 0) slotbits[0] = 0u;   // decodes to sigma=1
                __syncthreads();
            } else {
                red[tid] = (tid < 256) ? redzone[tid] : 0.f;
                if (tt < 16) s_sh[k * 16 + tt] = s[node * 16 + tt];
                else vec_sh[k * 48 + tt - 16] = vec[node * 48 + tt - 16];
                __syncthreads();
#pragma unroll
                for (int o = 256; o > 0; o >>= 1) {
                    if (tid < o) red[tid] = fmaxf(red[tid], red[tid + o]);
                    __syncthreads();
                }
                unsigned mb = __float_as_uint(red[0]);
                float iv;
                sigma_from_bits(mb, &sigma, &iv);
                if (blk == 0 && tid == 0) slotbits[l] = mb;
            }

            const float* W2 = rw2 + l * 32768;
            const float* b2 = rb2 + l * 1024;
            int f = tid >> 2, hq8 = tid & 3;       // f 0..127, h-octet 0..3
            int i = f >> 3, cc = f & 7;
            int strm = (cc == 0) ? 0 : (cc == 1) ? 1 : (cc <= 4) ? 2 : 3;
            int dd = (cc <= 1) ? 0 : (cc <= 4 ? cc - 2 : cc - 5);
            const float* wp = W2 + (size_t)(hq8 * 8) * 1024 + strm * 256 + i * 16;

            for (int pass = 0; pass < 2; ++pass) {
                int kb = pass * 4;
                float ft[4][16];
#pragma unroll
                for (int k2 = 0; k2 < 4; ++k2) {
                    if (strm <= 1) {
#pragma unroll
                        for (int qq = 0; qq < 4; ++qq) {
                            float4 x = *(const float4*)&s_sh[(kb + k2) * 16 + qq * 4];
                            ft[k2][qq * 4 + 0] = x.x; ft[k2][qq * 4 + 1] = x.y;
                            ft[k2][qq * 4 + 2] = x.z; ft[k2][qq * 4 + 3] = x.w;
                        }
                    } else {
#pragma unroll
                        for (int j = 0; j < 16; ++j)
                            ft[k2][j] = vec_sh[(kb + k2) * 48 + j * 3 + dd];
                    }
                }
                float outv[4][8];
#pragma unroll
                for (int k2 = 0; k2 < 4; ++k2)
#pragma unroll
                    for (int h8 = 0; h8 < 8; ++h8) outv[k2][h8] = 0.f;
#pragma unroll
                for (int h8 = 0; h8 < 8; ++h8) {
                    const float4* w4 = (const float4*)(wp + h8 * 1024);
                    float4 a0 = w4[0], a1 = w4[1], a2 = w4[2], a3 = w4[3];
                    float w[16] = {a0.x,a0.y,a0.z,a0.w, a1.x,a1.y,a1.z,a1.w,
                                   a2.x,a2.y,a2.z,a2.w, a3.x,a3.y,a3.z,a3.w};
#pragma unroll
                    for (int k2 = 0; k2 < 4; ++k2) {
                        float acc = 0.f;
#pragma unroll
                        for (int j = 0; j < 16; ++j) acc += w[j] * ft[k2][j];
                        outv[k2][h8] = acc;
                    }
                }
#pragma unroll
                for (int k2 = 0; k2 < 4; ++k2) {
                    f16x8 st;
#pragma unroll
                    for (int h8 = 0; h8 < 8; ++h8) st[h8] = (_Float16)(outv[k2][h8] * sigma);
                    *(f16x8*)(A2 + (size_t)(node0 + kb + k2) * 4096 + f * 32 + hq8 * 8) = st;
                }
                if (hq8 == 0) {
                    const float* bp = b2 + strm * 256 + i * 16;
                    float bw[16];
#pragma unroll
                    for (int qq = 0; qq < 4; ++qq) {
                        float4 x = *(const float4*)(bp + qq * 4);
                        bw[qq * 4 + 0] = x.x; bw[qq * 4 + 1] = x.y;
                        bw[qq * 4 + 2] = x.z; bw[qq * 4 + 3] = x.w;
                    }
#pragma unroll
                    for (int k2 = 0; k2 < 4; ++k2) {
                        float acc = 0.f;
#pragma unroll
                        for (int j = 0; j < 16; ++j) acc += bw[j] * ft[k2][j];
                        B2[(size_t)(node0 + kb + k2) * 128 + f] = acc * sigma;
                    }
                }
            }
        }
        __threadfence();
        grid.sync();

        // ================= EDGE: MFMA message pass =================
        {
            const float* w1 = rw1 + l * 32;
            const float* b1 = rb1 + l * 32;
            int xcd = blk & 7;
            int t = blk >> 3;                    // 0..31
            int b = xcd * 4 + (t >> 3);
            int sgrp = t & 7;
            int w = tid >> 6;                    // 0..7
            int wd = w >> 1, wfh = w & 1;
            int lane = tid & 63;
            int q = lane >> 4, col = lane & 15;
            int dst = wd * 16 + col;
            float qodd = (float)(q & 1);
            float o1 = qodd;
            float* pos_sh = smem;                // [192]
            if (tid < NN * 3) pos_sh[tid] = pos[(size_t)b * NN * 3 + tid];
            __syncthreads();

            float pdx = pos_sh[dst * 3 + 0], pdy = pos_sh[dst * 3 + 1], pdz = pos_sh[dst * 3 + 2];
            float w1r[8], b1r[8];
#pragma unroll
            for (int j = 0; j < 8; ++j) { w1r[j] = w1[q * 8 + j]; b1r[j] = b1[q * 8 + j]; }

            float sigma, invs;
            sigma_from_bits(slotbits[l], &sigma, &invs);

            f32x4 acc[4][4];
#pragma unroll
            for (int mt = 0; mt < 4; ++mt)
#pragma unroll
                for (int u = 0; u < 4; ++u) acc[mt][u] = (f32x4){0.f, 0.f, 0.f, 0.f};
            float ms_p[4] = {0.f, 0.f, 0.f, 0.f};
            float mv_p[4][3];
#pragma unroll
            for (int mt = 0; mt < 4; ++mt) { mv_p[mt][0] = 0.f; mv_p[mt][1] = 0.f; mv_p[mt][2] = 0.f; }

            const _Float16* Ab = A2 + (size_t)b * NN * 4096 + (size_t)wfh * 2048 + col * 32 + q * 8;
            const float* Bb = B2 + (size_t)b * NN * 128 + wfh * 64 + q * 4;

            for (int src = sgrp * 8; src < sgrp * 8 + 8; ++src) {
                float psx = pos_sh[src * 3 + 0];
                float psy = pos_sh[src * 3 + 1];
                float psz = pos_sh[src * 3 + 2];
                float dx = pdx - psx, dy = pdy - psy, dz = pdz - psz;
                float r = sqrtf(dx * dx + dy * dy + dz * dz);
                float inv = 1.f / (r + EPSV);
                float ux = dx * inv, uy = dy * inv, uz = dz * inv;
                float vmask = (dst == src) ? 0.f : 1.f;

                f16x8 bf0, bf1, bf2, bf3;
#pragma unroll
                for (int j = 0; j < 8; ++j) {
                    float hv = fmaxf(fmaf(r, w1r[j], b1r[j]), 0.f) * vmask;
                    bf0[j] = (_Float16)hv;
                    bf1[j] = (_Float16)(hv * ux);
                    bf2[j] = (_Float16)(hv * uy);
                    bf3[j] = (_Float16)(hv * uz);
                }

                const _Float16* Af = Ab + (size_t)src * 4096;
#pragma unroll
                for (int mt = 0; mt < 4; ++mt) {
                    f16x8 af = *(const f16x8*)(Af + mt * 16 * 32);
                    acc[mt][0] = __builtin_amdgcn_mfma_f32_16x16x32_f16(af, bf0, acc[mt][0], 0, 0, 0);
                    acc[mt][1] = __builtin_amdgcn_mfma_f32_16x16x32_f16(af, bf1, acc[mt][1], 0, 0, 0);
                    acc[mt][2] = __builtin_amdgcn_mfma_f32_16x16x32_f16(af, bf2, acc[mt][2], 0, 0, 0);
                    acc[mt][3] = __builtin_amdgcn_mfma_f32_16x16x32_f16(af, bf3, acc[mt][3], 0, 0, 0);
                }

                float s0  = qodd ? uz : 1.f;
                float zx  = qodd ? 0.f : ux;
                float zy  = qodd ? 0.f : uy;
                float exu = qodd ? 1.f : ux;
                float euy = qodd ? 0.f : uy;
                float euz = qodd ? 0.f : uz;
                const float* Bf = Bb + (size_t)src * 128;
#pragma unroll
                for (int mt = 0; mt < 4; ++mt) {
                    float4 bv = *(const float4*)(Bf + mt * 16);
                    float t0 = bv.x * vmask, t1 = bv.y * vmask, t2 = bv.z * vmask, t3 = bv.w * vmask;
                    ms_p[mt]    += t0 * s0 + t2 * zx + t3 * zy;
                    mv_p[mt][0] += t1 * exu;
                    mv_p[mt][1] += t1 * euy + t2 * o1;
                    mv_p[mt][2] += t1 * euz + t3 * o1;
                }
            }

            if ((q & 1) == 0) {
#pragma unroll
                for (int mt = 0; mt < 4; ++mt) {
                    ms_p[mt]    += acc[mt][0][0] + acc[mt][1][2] + acc[mt][2][3];
                    mv_p[mt][0] += acc[mt][1][1];
                    mv_p[mt][1] += acc[mt][2][1];
                    mv_p[mt][2] += acc[mt][3][1];
                }
            } else {
#pragma unroll
                for (int mt = 0; mt < 4; ++mt) {
                    ms_p[mt]    += acc[mt][3][0];
                    mv_p[mt][0] += acc[mt][0][1];
                    mv_p[mt][1] += acc[mt][0][2];
                    mv_p[mt][2] += acc[mt][0][3];
                }
            }

#pragma unroll
            for (int mt = 0; mt < 4; ++mt) {
                ms_p[mt] = ms_p[mt] * invs + __shfl_xor(ms_p[mt] * invs, 16, 64);
                mv_p[mt][0] = mv_p[mt][0] * invs + __shfl_xor(mv_p[mt][0] * invs, 16, 64);
                mv_p[mt][1] = mv_p[mt][1] * invs + __shfl_xor(mv_p[mt][1] * invs, 16, 64);
                mv_p[mt][2] = mv_p[mt][2] * invs + __shfl_xor(mv_p[mt][2] * invs, 16, 64);
            }

            if ((q & 1) == 0) {
                int node = b * NN + dst;
#pragma unroll
                for (int mt = 0; mt < 4; ++mt) {
                    int i2 = (wfh * 4 + mt) * 2 + (q >> 1);
                    aggs[(size_t)sgrp * 32768 + node * 16 + i2] = ms_p[mt];
                    float* vp = aggv + (size_t)sgrp * 98304 + node * 48 + i2 * 3;
                    vp[0] = mv_p[mt][0]; vp[1] = mv_p[mt][1]; vp[2] = mv_p[mt][2];
                }
            }
        }
        __threadfence();
        grid.sync();

        // ================= UPDATE (layers 0,1) =================
        if (l < 2) {
            const float* wsL = sws + l * 256;
            const float* wvL = swv + l * 256;
            float* ash = smem;          // [8][16]
            float* avh = smem + 128;    // [8][48]
            float* red = smem + 512;    // [512]
            int node0 = blk * 8;
            int k = tid >> 6, tt = tid & 63;
            int node = node0 + k;
            if (tt < 16) {
                float a = 0.f;
#pragma unroll
                for (int p = 0; p < 8; ++p) a += aggs[(size_t)p * 32768 + node * 16 + tt];
                ash[k * 16 + tt] = a;
            } else {
                int qq = tt - 16;
                float a = 0.f;
#pragma unroll
                for (int p = 0; p < 8; ++p) a += aggv[(size_t)p * 98304 + node * 48 + qq];
                avh[k * 48 + qq] = a;
            }
            __syncthreads();
            float val;
            if (tt < 16) {
                float acc = 0.f;
#pragma unroll
                for (int c = 0; c < 16; ++c) acc += ash[k * 16 + c] * wsL[c * 16 + tt];
                val = s[node * 16 + tt] + fmaxf(acc, 0.f);
                s[node * 16 + tt] = val;
            } else {
                int qq = tt - 16, e = qq / 3, d = qq % 3;
                float acc = 0.f;
#pragma unroll
                for (int c = 0; c < 16; ++c) acc += avh[k * 48 + c * 3 + d] * wvL[c * 16 + e];
                val = vec[node * 48 + qq] + acc;
                vec[node * 48 + qq] = val;
            }
            red[tid] = fabsf(val);
            __syncthreads();
#pragma unroll
            for (int o = 256; o > 0; o >>= 1) {
                if (tid < o) red[tid] = fmaxf(red[tid], red[tid + o]);
                __syncthreads();
            }
            if (tid == 0) redzone[blk] = red[0];
            __threadfence();
            grid.sync();
        }
    }

    // ================= OUT =================
    {
        const float* wvL = swv + 512;
        float* avh = smem;          // [8][48]
        float* vn  = smem + 384;    // [8][48]
        int node0 = blk * 8;
        int k = tid >> 6, t = tid & 63;
        int node = node0 + k;
        if (t < 48) {
            float a = 0.f;
#pragma unroll
            for (int p = 0; p < 8; ++p) a += aggv[(size_t)p * 98304 + node * 48 + t];
            avh[k * 48 + t] = a;
        }
        __syncthreads();
        if (t < 48) {
            int e = t / 3, d = t % 3;
            float acc = 0.f;
#pragma unroll
            for (int c = 0; c < 16; ++c) acc += avh[k * 48 + c * 3 + d] * wvL[c * 16 + e];
            vn[k * 48 + t] = (vec[node * 48 + t] + acc) * wvo[e];
        }
        __syncthreads();
        if (t < 3) {
            float acc = 0.f;
#pragma unroll
            for (int e = 0; e < 16; ++e) acc += vn[k * 48 + e * 3 + t];
            out[node * 3 + t] = acc + pos[node * 3 + t];
        }
    }
}

extern "C" void kernel_launch(void* const* d_in, const int* in_sizes, int n_in,
                              void* d_out, int out_size, void* d_ws, size_t ws_size,
                              hipStream_t stream) {
    const float* pos = (const float*)d_in[0];
    const float* v   = (const float*)d_in[1];
    const float* z   = (const float*)d_in[2];
    const float* w_s_in = (const float*)d_in[3];
    const float* w_v_in = (const float*)d_in[4];
    const float* rw1 = (const float*)d_in[5];
    const float* rb1 = (const float*)d_in[6];
    const float* rw2 = (const float*)d_in[7];
    const float* rb2 = (const float*)d_in[8];
    const float* sws = (const float*)d_in[9];
    const float* swv = (const float*)d_in[10];
    const float* wvo = (const float*)d_in[11];
    float* out = (float*)d_out;
    float* wsf = (float*)d_ws;

    void* args[] = {
        (void*)&pos, (void*)&v, (void*)&z, (void*)&w_s_in, (void*)&w_v_in,
        (void*)&rw1, (void*)&rb1, (void*)&rw2, (void*)&rb2,
        (void*)&sws, (void*)&swv, (void*)&wvo, (void*)&out, (void*)&wsf
    };
    hipLaunchCooperativeKernel((const void*)k_all, dim3(256), dim3(512),
                               args, 0, stream);
}

// Round 6
// 129.754 us; speedup vs baseline: 6.8272x; 6.8272x over previous
//
#include <hip/hip_runtime.h>

#define NF 16
#define HIDN 32
#define NB 32
#define NN 64
#define EPSV 1e-8f

typedef _Float16 f16x8 __attribute__((ext_vector_type(8)));
typedef float f32x4 __attribute__((ext_vector_type(4)));

// Workspace layout (float offsets), all regions overwritten before read each call:
//   slotbits : 0    (16)   per-layer sigma bits
//   redzone  : 16   (512)  per-block absmax partials (update writes, pre reduces)
//   s        : 576  (32768)
//   vec      : 33344 (98304)
//   aggs     : 131648 (8*32768)
//   aggv     : 393792 (8*98304)
//   B2       : 1180224 (2048*128 fp32, sigma-scaled)
//   A2       : 1442368 (2048*4096 fp16, sigma-scaled)
#define SLOT_OFF 0
#define RED_OFF  16
#define S_OFF    576
#define VEC_OFF  33344
#define AGGS_OFF 131648
#define AGGV_OFF 393792
#define B2_OFF   1180224
#define A2_OFF   1442368

__device__ __forceinline__ void sigma_from_bits(unsigned mb, float* sig, float* invs) {
    int ex = (int)((mb >> 23) & 0xFF);
    if (ex == 0) { *sig = 1.f; *invs = 1.f; return; }
    *sig  = __uint_as_float((unsigned)(253 - ex) << 23);  // 2^(126-ex)
    *invs = __uint_as_float((unsigned)(ex + 1) << 23);    // 2^(ex-126)
}

// grid 256 x 512 threads; 8 nodes/block (2 passes of 4).
// Thread (f = tid>>2, hq8 = tid&3) owns an 8-h slice of one output row f.
template <int IS_L0>
__global__ __launch_bounds__(512) void k_pre(
        const float* __restrict__ z, const float* __restrict__ v,
        const float* __restrict__ w_s_in, const float* __restrict__ w_v_in,
        float* __restrict__ s, float* __restrict__ vec,
        const float* __restrict__ W2, const float* __restrict__ b2,
        const float* __restrict__ redzone, unsigned* __restrict__ slot_out,
        _Float16* __restrict__ A2, float* __restrict__ B2) {
    int node0 = blockIdx.x * 8;
    int tid = threadIdx.x;
    __shared__ float s_sh[8][16];
    __shared__ float vec_t[3][8][16];   // transposed: [d][node][channel]
    __shared__ float red[512];

    float sigma, invs;
    {
        int k = tid >> 6, tt = tid & 63;
        int node = node0 + k;
        if (IS_L0) {
            sigma = 1.f; invs = 1.f;
            if (tid == 0 && blockIdx.x == 0) *slot_out = 0u;  // decodes sigma=1
            if (tt < 16) {
                float val = z[node] * w_s_in[tt];
                s_sh[k][tt] = val;
                s[node * 16 + tt] = val;
            } else {
                int q = tt - 16, c = q / 3, d = q % 3;
                float val = v[node * 3 + d] * w_v_in[c];
                vec_t[d][k][c] = val;
                vec[node * 48 + q] = val;
            }
            __syncthreads();
        } else {
            red[tid] = redzone[tid];
            if (tt < 16) s_sh[k][tt] = s[node * 16 + tt];
            else {
                int q = tt - 16, c = q / 3, d = q % 3;
                vec_t[d][k][c] = vec[node * 48 + q];
            }
            __syncthreads();
#pragma unroll
            for (int o = 256; o > 0; o >>= 1) {
                if (tid < o) red[tid] = fmaxf(red[tid], red[tid + o]);
                __syncthreads();
            }
            unsigned mb = __float_as_uint(red[0]);
            sigma_from_bits(mb, &sigma, &invs);
            if (tid == 0) *slot_out = mb;
        }
    }

    int f = tid >> 2, hq8 = tid & 3;       // f 0..127, h-octet 0..3
    int i = f >> 3, cc = f & 7;
    int strm = (cc == 0) ? 0 : (cc == 1) ? 1 : (cc <= 4) ? 2 : 3;
    int dd = (cc <= 1) ? 0 : (cc <= 4 ? cc - 2 : cc - 5);
    const float* wp = W2 + (size_t)(hq8 * 8) * 1024 + strm * 256 + i * 16;

    for (int pass = 0; pass < 2; ++pass) {
        int kb = pass * 4;
        float ft[4][16];
#pragma unroll
        for (int k2 = 0; k2 < 4; ++k2) {
            const float* srcp = (strm <= 1) ? &s_sh[kb + k2][0] : &vec_t[dd][kb + k2][0];
#pragma unroll
            for (int qq = 0; qq < 4; ++qq) {
                float4 x = *(const float4*)(srcp + qq * 4);
                ft[k2][qq * 4 + 0] = x.x; ft[k2][qq * 4 + 1] = x.y;
                ft[k2][qq * 4 + 2] = x.z; ft[k2][qq * 4 + 3] = x.w;
            }
        }
        float outv[4][8];
#pragma unroll
        for (int k2 = 0; k2 < 4; ++k2)
#pragma unroll
            for (int h8 = 0; h8 < 8; ++h8) outv[k2][h8] = 0.f;
#pragma unroll
        for (int h8 = 0; h8 < 8; ++h8) {
            const float4* w4 = (const float4*)(wp + h8 * 1024);
            float4 a0 = w4[0], a1 = w4[1], a2 = w4[2], a3 = w4[3];
            float w[16] = {a0.x,a0.y,a0.z,a0.w, a1.x,a1.y,a1.z,a1.w,
                           a2.x,a2.y,a2.z,a2.w, a3.x,a3.y,a3.z,a3.w};
#pragma unroll
            for (int k2 = 0; k2 < 4; ++k2) {
                float acc = 0.f;
#pragma unroll
                for (int j = 0; j < 16; ++j) acc += w[j] * ft[k2][j];
                outv[k2][h8] = acc;
            }
        }
#pragma unroll
        for (int k2 = 0; k2 < 4; ++k2) {
            f16x8 st;
#pragma unroll
            for (int h8 = 0; h8 < 8; ++h8) st[h8] = (_Float16)(outv[k2][h8] * sigma);
            *(f16x8*)(A2 + (size_t)(node0 + kb + k2) * 4096 + f * 32 + hq8 * 8) = st;
        }
        if (hq8 == 0) {
            const float* bp = b2 + strm * 256 + i * 16;
            float bw[16];
#pragma unroll
            for (int qq = 0; qq < 4; ++qq) {
                float4 x = *(const float4*)(bp + qq * 4);
                bw[qq * 4 + 0] = x.x; bw[qq * 4 + 1] = x.y;
                bw[qq * 4 + 2] = x.z; bw[qq * 4 + 3] = x.w;
            }
#pragma unroll
            for (int k2 = 0; k2 < 4; ++k2) {
                float acc = 0.f;
#pragma unroll
                for (int j = 0; j < 16; ++j) acc += bw[j] * ft[k2][j];
                B2[(size_t)(node0 + kb + k2) * 128 + f] = acc * sigma;
            }
        }
    }
}

__global__ __launch_bounds__(256) void k_edge(
        const float* __restrict__ pos,
        const _Float16* __restrict__ A2, const float* __restrict__ B2,
        const float* __restrict__ w1, const float* __restrict__ b1,
        const unsigned* __restrict__ slot,
        float* __restrict__ aggs, float* __restrict__ aggv) {
    // grid 512 = 8 xcd * 4 b * 8 sgrp * 2 fhalf
    int blk = blockIdx.x;
    int xcd = blk & 7;
    int t = blk >> 3;                    // 0..63
    int b = xcd * 4 + (t >> 4);
    int rem = t & 15;
    int sgrp = rem >> 1, wfh = rem & 1;
    int wd = threadIdx.x >> 6;           // dst tile 0..3
    int lane = threadIdx.x & 63;
    int q = lane >> 4, col = lane & 15;
    int dst = wd * 16 + col;
    float qodd = (float)(q & 1);
    float o1 = qodd;

    __shared__ float pos_sh[NN * 3];
    if (threadIdx.x < NN * 3) pos_sh[threadIdx.x] = pos[(size_t)b * NN * 3 + threadIdx.x];
    __syncthreads();

    float pdx = pos_sh[dst * 3 + 0], pdy = pos_sh[dst * 3 + 1], pdz = pos_sh[dst * 3 + 2];
    float w1r[8], b1r[8];
#pragma unroll
    for (int j = 0; j < 8; ++j) { w1r[j] = w1[q * 8 + j]; b1r[j] = b1[q * 8 + j]; }

    float sigma, invs;
    sigma_from_bits(*slot, &sigma, &invs);

    f32x4 acc[4][4];
#pragma unroll
    for (int mt = 0; mt < 4; ++mt)
#pragma unroll
        for (int u = 0; u < 4; ++u) acc[mt][u] = (f32x4){0.f, 0.f, 0.f, 0.f};
    float ms_p[4] = {0.f, 0.f, 0.f, 0.f};
    float mv_p[4][3];
#pragma unroll
    for (int mt = 0; mt < 4; ++mt) { mv_p[mt][0] = 0.f; mv_p[mt][1] = 0.f; mv_p[mt][2] = 0.f; }

    const _Float16* Ab = A2 + (size_t)b * NN * 4096 + (size_t)wfh * 2048 + col * 32 + q * 8;
    const float* Bb = B2 + (size_t)b * NN * 128 + wfh * 64 + q * 4;

    for (int src = sgrp * 8; src < sgrp * 8 + 8; ++src) {
        float psx = pos_sh[src * 3 + 0];
        float psy = pos_sh[src * 3 + 1];
        float psz = pos_sh[src * 3 + 2];
        float dx = pdx - psx, dy = pdy - psy, dz = pdz - psz;
        float r = sqrtf(dx * dx + dy * dy + dz * dz);
        float inv = 1.f / (r + EPSV);
        float ux = dx * inv, uy = dy * inv, uz = dz * inv;
        float vmask = (dst == src) ? 0.f : 1.f;

        f16x8 bf0, bf1, bf2, bf3;
#pragma unroll
        for (int j = 0; j < 8; ++j) {
            float hv = fmaxf(fmaf(r, w1r[j], b1r[j]), 0.f) * vmask;
            bf0[j] = (_Float16)hv;
            bf1[j] = (_Float16)(hv * ux);
            bf2[j] = (_Float16)(hv * uy);
            bf3[j] = (_Float16)(hv * uz);
        }

        const _Float16* Af = Ab + (size_t)src * 4096;
#pragma unroll
        for (int mt = 0; mt < 4; ++mt) {
            f16x8 af = *(const f16x8*)(Af + mt * 16 * 32);
            acc[mt][0] = __builtin_amdgcn_mfma_f32_16x16x32_f16(af, bf0, acc[mt][0], 0, 0, 0);
            acc[mt][1] = __builtin_amdgcn_mfma_f32_16x16x32_f16(af, bf1, acc[mt][1], 0, 0, 0);
            acc[mt][2] = __builtin_amdgcn_mfma_f32_16x16x32_f16(af, bf2, acc[mt][2], 0, 0, 0);
            acc[mt][3] = __builtin_amdgcn_mfma_f32_16x16x32_f16(af, bf3, acc[mt][3], 0, 0, 0);
        }

        float s0  = qodd ? uz : 1.f;
        float zx  = qodd ? 0.f : ux;
        float zy  = qodd ? 0.f : uy;
        float exu = qodd ? 1.f : ux;
        float euy = qodd ? 0.f : uy;
        float euz = qodd ? 0.f : uz;
        const float* Bf = Bb + (size_t)src * 128;
#pragma unroll
        for (int mt = 0; mt < 4; ++mt) {
            float4 bv = *(const float4*)(Bf + mt * 16);
            float t0 = bv.x * vmask, t1 = bv.y * vmask, t2 = bv.z * vmask, t3 = bv.w * vmask;
            ms_p[mt]    += t0 * s0 + t2 * zx + t3 * zy;
            mv_p[mt][0] += t1 * exu;
            mv_p[mt][1] += t1 * euy + t2 * o1;
            mv_p[mt][2] += t1 * euz + t3 * o1;
        }
    }

    if ((q & 1) == 0) {
#pragma unroll
        for (int mt = 0; mt < 4; ++mt) {
            ms_p[mt]    += acc[mt][0][0] + acc[mt][1][2] + acc[mt][2][3];
            mv_p[mt][0] += acc[mt][1][1];
            mv_p[mt][1] += acc[mt][2][1];
            mv_p[mt][2] += acc[mt][3][1];
        }
    } else {
#pragma unroll
        for (int mt = 0; mt < 4; ++mt) {
            ms_p[mt]    += acc[mt][3][0];
            mv_p[mt][0] += acc[mt][0][1];
            mv_p[mt][1] += acc[mt][0][2];
            mv_p[mt][2] += acc[mt][0][3];
        }
    }

#pragma unroll
    for (int mt = 0; mt < 4; ++mt) {
        ms_p[mt] = ms_p[mt] * invs + __shfl_xor(ms_p[mt] * invs, 16, 64);
        mv_p[mt][0] = mv_p[mt][0] * invs + __shfl_xor(mv_p[mt][0] * invs, 16, 64);
        mv_p[mt][1] = mv_p[mt][1] * invs + __shfl_xor(mv_p[mt][1] * invs, 16, 64);
        mv_p[mt][2] = mv_p[mt][2] * invs + __shfl_xor(mv_p[mt][2] * invs, 16, 64);
    }

    if ((q & 1) == 0) {
        int node = b * NN + dst;
#pragma unroll
        for (int mt = 0; mt < 4; ++mt) {
            int i2 = (wfh * 4 + mt) * 2 + (q >> 1);
            aggs[(size_t)sgrp * 32768 + node * 16 + i2] = ms_p[mt];
            float* vp = aggv + (size_t)sgrp * 98304 + node * 48 + i2 * 3;
            vp[0] = mv_p[mt][0]; vp[1] = mv_p[mt][1]; vp[2] = mv_p[mt][2];
        }
    }
}

__global__ __launch_bounds__(256) void k_update(
        const float* __restrict__ aggs, const float* __restrict__ aggv,
        const float* __restrict__ ws, const float* __restrict__ wv,
        float* __restrict__ s, float* __restrict__ vec, float* __restrict__ redzone) {
    int node0 = blockIdx.x * 4;
    int tid = threadIdx.x;
    int k = tid >> 6, tt = tid & 63;
    int node = node0 + k;
    __shared__ float ash[4][16];
    __shared__ float avh[4][48];
    if (tt < 16) {
        float a = 0.f;
#pragma unroll
        for (int p = 0; p < 8; ++p) a += aggs[(size_t)p * 32768 + node * 16 + tt];
        ash[k][tt] = a;
    } else {
        int qq = tt - 16;
        float a = 0.f;
#pragma unroll
        for (int p = 0; p < 8; ++p) a += aggv[(size_t)p * 98304 + node * 48 + qq];
        avh[k][qq] = a;
    }
    __syncthreads();
    float val;
    if (tt < 16) {
        float acc = 0.f;
#pragma unroll
        for (int c = 0; c < 16; ++c) acc += ash[k][c] * ws[c * 16 + tt];
        val = s[node * 16 + tt] + fmaxf(acc, 0.f);
        s[node * 16 + tt] = val;
    } else {
        int qq = tt - 16, e = qq / 3, d = qq % 3;
        float acc = 0.f;
#pragma unroll
        for (int c = 0; c < 16; ++c) acc += avh[k][c * 3 + d] * wv[c * 16 + e];
        val = vec[node * 48 + qq] + acc;
        vec[node * 48 + qq] = val;
    }
    __shared__ float red[256];
    red[tid] = fabsf(val);
    __syncthreads();
#pragma unroll
    for (int o = 128; o > 0; o >>= 1) {
        if (tid < o) red[tid] = fmaxf(red[tid], red[tid + o]);
        __syncthreads();
    }
    if (tid == 0) redzone[blockIdx.x] = red[0];
}

__global__ __launch_bounds__(256) void k_out(
        const float* __restrict__ aggv, const float* __restrict__ wv,
        const float* __restrict__ wvo, const float* __restrict__ vec,
        const float* __restrict__ pos, float* __restrict__ out) {
    int node0 = blockIdx.x * 4;
    int tid = threadIdx.x;
    int k = tid >> 6, t = tid & 63;
    int node = node0 + k;
    __shared__ float avh[4][48];
    __shared__ float vn[4][48];
    if (t < 48) {
        float a = 0.f;
#pragma unroll
        for (int p = 0; p < 8; ++p) a += aggv[(size_t)p * 98304 + node * 48 + t];
        avh[k][t] = a;
    }
    __syncthreads();
    if (t < 48) {
        int e = t / 3, d = t % 3;
        float acc = 0.f;
#pragma unroll
        for (int c = 0; c < 16; ++c) acc += avh[k][c * 3 + d] * wv[c * 16 + e];
        vn[k][t] = (vec[node * 48 + t] + acc) * wvo[e];
    }
    __syncthreads();
    if (t < 3) {
        float acc = 0.f;
#pragma unroll
        for (int e = 0; e < 16; ++e) acc += vn[k][e * 3 + t];
        out[node * 3 + t] = acc + pos[node * 3 + t];
    }
}

extern "C" void kernel_launch(void* const* d_in, const int* in_sizes, int n_in,
                              void* d_out, int out_size, void* d_ws, size_t ws_size,
                              hipStream_t stream) {
    const float* pos = (const float*)d_in[0];
    const float* v   = (const float*)d_in[1];
    const float* z   = (const float*)d_in[2];
    const float* w_s_in = (const float*)d_in[3];
    const float* w_v_in = (const float*)d_in[4];
    const float* rw1 = (const float*)d_in[5];
    const float* rb1 = (const float*)d_in[6];
    const float* rw2 = (const float*)d_in[7];
    const float* rb2 = (const float*)d_in[8];
    const float* sws = (const float*)d_in[9];
    const float* swv = (const float*)d_in[10];
    const float* wvo = (const float*)d_in[11];
    float* out = (float*)d_out;

    float* wsf  = (float*)d_ws;
    unsigned* slotbits = (unsigned*)(wsf + SLOT_OFF);
    float* redzone = wsf + RED_OFF;
    float* s    = wsf + S_OFF;
    float* vec  = wsf + VEC_OFF;
    float* aggs = wsf + AGGS_OFF;
    float* aggv = wsf + AGGV_OFF;
    float* B2   = wsf + B2_OFF;
    _Float16* A2 = (_Float16*)(wsf + A2_OFF);

    k_pre<1><<<256, 512, 0, stream>>>(z, v, w_s_in, w_v_in, s, vec,
                                      rw2, rb2, redzone, slotbits, A2, B2);
    k_edge<<<512, 256, 0, stream>>>(pos, A2, B2, rw1, rb1, slotbits, aggs, aggv);

    k_update<<<512, 256, 0, stream>>>(aggs, aggv, sws, swv, s, vec, redzone);
    k_pre<0><<<256, 512, 0, stream>>>(z, v, w_s_in, w_v_in, s, vec,
                                      rw2 + 32768, rb2 + 1024, redzone, slotbits + 1, A2, B2);
    k_edge<<<512, 256, 0, stream>>>(pos, A2, B2, rw1 + 32, rb1 + 32, slotbits + 1, aggs, aggv);

    k_update<<<512, 256, 0, stream>>>(aggs, aggv, sws + 256, swv + 256, s, vec, redzone);
    k_pre<0><<<256, 512, 0, stream>>>(z, v, w_s_in, w_v_in, s, vec,
                                      rw2 + 65536, rb2 + 2048, redzone, slotbits + 2, A2, B2);
    k_edge<<<512, 256, 0, stream>>>(pos, A2, B2, rw1 + 64, rb1 + 64, slotbits + 2, aggs, aggv);

    k_out<<<512, 256, 0, stream>>>(aggv, swv + 512, wvo, vec, pos, out);
}